// Round 1
// 843.856 us; speedup vs baseline: 1.0307x; 1.0307x over previous
//
#include <hip/hip_runtime.h>
#include <hip/hip_bf16.h>
#include <math.h>

#define S_DIM 16
#define O_DIM 8
#define J_DIM 32
#define B_DIM 4096
#define HID 240
#define OHID 512

typedef __attribute__((ext_vector_type(8))) short bf16x8;
typedef __attribute__((ext_vector_type(4))) float f32x4;
#define MFMA16(a,b,c) __builtin_amdgcn_mfma_f32_16x16x32_bf16((a),(b),(c),0,0,0)

// ws layout (float offsets for fp32 part)
#define WS_XPRED   0                                  // [B,16]
#define WS_INNO    (WS_XPRED + B_DIM*S_DIM)           // [B,8]
#define WS_FEATS   (WS_INNO + B_DIM*O_DIM)            // [B,48]
#define WS_XIN0    (WS_FEATS + B_DIM*48)              // [B,240]
#define WS_GH      (WS_XIN0 + B_DIM*HID)              // [960]
#define WS_WB_OFF  ((WS_GH + 960) * 4)                // byte offset: bf16 weights
// bf16 weights: Wihb[768][256], Wo1b[512][256], Wo2b[128][512]

// out layout (float offsets)
#define OUT_X      0
#define OUT_P      (B_DIM*S_DIM)                      // 65536
#define OUT_REG    (2*B_DIM*S_DIM)                    // 131072
#define OUT_ENS    (2*B_DIM*S_DIM + 1)                // 131073

// ---------------------------------------------------------------------------
// aux+pre_a merged: blocks [0,1536) cast weights to bf16 (K-padded) + GRU gh
// precompute; blocks [1536,1552) do the Kalman prefix per b.
// ---------------------------------------------------------------------------
__global__ void k_aux_pre(const float* __restrict__ W_ih, const float* __restrict__ W_hh,
                          const float* __restrict__ b_ih, const float* __restrict__ b_hh,
                          const float* __restrict__ h_init,
                          const float* __restrict__ W_o1, const float* __restrict__ W_o2,
                          __hip_bfloat16* __restrict__ Wihb, __hip_bfloat16* __restrict__ Wo1b,
                          __hip_bfloat16* __restrict__ Wo2b, float* __restrict__ ghb,
                          const float* __restrict__ y, const float* __restrict__ xprev,
                          const float* __restrict__ F, const float* __restrict__ Hm,
                          float* __restrict__ x_pred, float* __restrict__ inno,
                          float* __restrict__ feats)
{
    __shared__ float sF[256], sH[128];
    const int tid = threadIdx.x;
    if (blockIdx.x < 1536) {
        int t = blockIdx.x * 256 + tid;
        if (t < 768*256) {
            int n = t >> 8, k = t & 255;
            float v = (n < 720 && k < 240) ? W_ih[n*240 + k] : 0.0f;
            Wihb[t] = __float2bfloat16(v);
        } else if (t < 768*256 + 512*256) {
            int u = t - 768*256;
            int n = u >> 8, k = u & 255;
            float v = (k < 240) ? W_o1[n*240 + k] : 0.0f;
            Wo1b[u] = __float2bfloat16(v);
        } else if (t < 768*256 + 512*256 + 128*512) {
            int u = t - 768*256 - 512*256;
            Wo2b[u] = __float2bfloat16(W_o2[u]);
        }
        if (t < 720) {
            float a = b_hh[t];
            const float* wr = W_hh + t*240;
            for (int k = 0; k < 240; k++) a = fmaf(h_init[k], wr[k], a);
            if (t < 480) {
                ghb[t] = b_ih[t] + a;            // r/z gates: bias fully folded
            } else {
                ghb[t] = b_ih[t];                // n gate: additive part
                ghb[t + 240] = a;                // n gate: part multiplied by r
            }
        }
        return;
    }
    // ---- pre_a part ----
    sF[tid] = F[tid];
    if (tid < 128) sH[tid] = Hm[tid];
    __syncthreads();
    int b = (blockIdx.x - 1536) * 256 + tid;
    float xf[16], xp[16], inn[8];
    #pragma unroll
    for (int s = 0; s < 16; s++) xf[s] = xprev[b*16 + s];
    #pragma unroll
    for (int s = 0; s < 16; s++) {
        float a = 0.f;
        #pragma unroll
        for (int k = 0; k < 16; k++) a = fmaf(xf[k], sF[s*16 + k], a);
        xp[s] = a;
    }
    #pragma unroll
    for (int o = 0; o < 8; o++) {
        float a = 0.f;
        #pragma unroll
        for (int k = 0; k < 16; k++) a = fmaf(xp[k], sH[o*16 + k], a);
        inn[o] = y[b*8 + o] - a;
    }
    #pragma unroll
    for (int s = 0; s < 16; s++) x_pred[b*16 + s] = xp[s];
    #pragma unroll
    for (int o = 0; o < 8; o++) inno[b*8 + o] = inn[o];
    float* fb = feats + b*48;
    #pragma unroll
    for (int s = 0; s < 16; s++) fb[s] = xf[s] - xp[s];
    #pragma unroll
    for (int o = 0; o < 8; o++) fb[16 + o] = inn[o];
    #pragma unroll
    for (int s = 0; s < 16; s++) fb[24 + s] = 0.f;
    #pragma unroll
    for (int o = 0; o < 8; o++) fb[40 + o] = inn[o];
}

// ---------------------------------------------------------------------------
// pre_b: x_in0 = relu(feats @ W_fc^T + b_fc)
// ---------------------------------------------------------------------------
__global__ void k_pre_b(const float* __restrict__ feats, const float* __restrict__ Wfc,
                        const float* __restrict__ bfc, float* __restrict__ x_in0)
{
    int t = blockIdx.x * 256 + threadIdx.x;
    int b = t / 240, h = t - b*240;
    const float* fb = feats + b*48;
    const float* wr = Wfc + h*48;
    float a = bfc[h];
    #pragma unroll
    for (int k = 0; k < 48; k += 4) {
        const float4 f4 = *(const float4*)&fb[k];
        const float4 w4 = *(const float4*)&wr[k];
        a = fmaf(f4.x, w4.x, fmaf(f4.y, w4.y, fmaf(f4.z, w4.z, fmaf(f4.w, w4.w, a))));
    }
    x_in0[t] = fmaxf(a, 0.f);
}

// ---------------------------------------------------------------------------
// main: bf16 MFMA fused chain. 32 (j,b)-rows/block (2 M-tiles), 4 waves.
// LDS 38.9KB (O1s overlays Xs+Hs after GEMM2-acc barrier) -> 4 blocks/CU.
// u2 dropout mask precomputed into a 2KB LDS bitmask with coalesced float4
// loads issued at kernel start (was: 64 scalar HBM loads in GEMM2 epilogue).
// ---------------------------------------------------------------------------
#define XS_STRIDE 264   // 240+24 pad bf16: 528B row -> banks offset 4/row (2-way, free)
#define O1_STRIDE 520   // 512+8 pad bf16: 1040B row -> same property

// LDS byte map:
//   [0,16896)      Xs  [32][264] bf16
//   [16896,33792)  Hs  [32][264] bf16
//   [0,33280)      O1s [32][520] bf16   (overlays Xs+Hs after GEMM2-acc barrier)
//   [33792,35840)  Mbits[512] u32       (u2 keep-mask, bit f = flat row*512+n)
//   [35840,37888)  XPs [32][16] f32
//   [37888,38912)  InnoS [32][8] f32
__global__ __launch_bounds__(256, 4) void k_main(
    const float* __restrict__ x_in0, const float* __restrict__ u1,
    const float* __restrict__ u2,
    const __hip_bfloat16* __restrict__ Wihb, const float* __restrict__ ghb,
    const float* __restrict__ h_init,
    const __hip_bfloat16* __restrict__ Wo1b, const float* __restrict__ b_out1,
    const __hip_bfloat16* __restrict__ Wo2b, const float* __restrict__ b_out2,
    const float* __restrict__ x_pred, const float* __restrict__ inno,
    float* __restrict__ ens)
{
    __shared__ __align__(16) char smem[38912];
    __hip_bfloat16* Xs  = (__hip_bfloat16*)smem;            // [32][264]
    __hip_bfloat16* Hs  = (__hip_bfloat16*)(smem + 16896);  // [32][264]
    __hip_bfloat16* O1s = (__hip_bfloat16*)smem;            // [32][520], overlays Xs+Hs
    unsigned int* Mbits = (unsigned int*)(smem + 33792);    // [512]
    float* XPs   = (float*)(smem + 35840);                  // [32][16]
    float* InnoS = (float*)(smem + 37888);                  // [32][8]

    const int tid = threadIdx.x;
    const int j  = blockIdx.x >> 7;          // 128 blocks per j
    const int b0 = (blockIdx.x & 127) << 5;  // 32 b-rows per block

    // ---- phase 0a: u2 keep-mask -> Mbits (coalesced float4 over contiguous 64KB) ----
    {
        const float4* u2t = (const float4*)(u2 + ((size_t)(j*B_DIM + b0) << 9));
        const int sh = (tid & 7) * 4;
        #pragma unroll
        for (int it = 0; it < 16; ++it) {
            float4 q = u2t[tid + 256*it];
            unsigned int nib = (q.x > 0.65f ? 1u : 0u) | (q.y > 0.65f ? 2u : 0u)
                             | (q.z > 0.65f ? 4u : 0u) | (q.w > 0.65f ? 8u : 0u);
            unsigned int v = nib << sh;
            v |= __shfl_xor(v, 1);
            v |= __shfl_xor(v, 2);
            v |= __shfl_xor(v, 4);
            if ((tid & 7) == 0) Mbits[(tid >> 3) + 32*it] = v;
        }
    }

    // ---- phase 0b: stage masked bf16 X tile (float4, contiguous 30KB tiles) ----
    {
        const float4* xt = (const float4*)(x_in0 + b0*240);
        const float4* ut = (const float4*)(u1 + (size_t)(j*B_DIM + b0)*240);
        #pragma unroll
        for (int it = 0; it < 8; ++it) {
            int idx = tid + 256*it;
            if (idx < 1920) {
                float4 xv = xt[idx];
                float4 uv = ut[idx];
                int flat = idx * 4;
                int i = flat / 240;
                int h = flat - i*240;        // multiple of 4 (240%4==0)
                __hip_bfloat16 o[4];
                o[0] = __float2bfloat16(uv.x > 0.5f ? 2.0f*xv.x : 0.0f);
                o[1] = __float2bfloat16(uv.y > 0.5f ? 2.0f*xv.y : 0.0f);
                o[2] = __float2bfloat16(uv.z > 0.5f ? 2.0f*xv.z : 0.0f);
                o[3] = __float2bfloat16(uv.w > 0.5f ? 2.0f*xv.w : 0.0f);
                *(uint2*)&Xs[i*XS_STRIDE + h] = *(const uint2*)o;
            }
        }
    }
    // zero K-pad cols [240,256) for Xs and Hs (MFMA reads up to col 256)
    if (tid < 128) {
        int row = tid >> 2, c = 240 + ((tid & 3) << 2);
        uint2 z = {0u, 0u};
        *(uint2*)&Xs[row*XS_STRIDE + c] = z;
        *(uint2*)&Hs[row*XS_STRIDE + c] = z;
    }
    XPs[tid]       = x_pred[b0*16 + tid];
    XPs[tid + 256] = x_pred[b0*16 + tid + 256];
    InnoS[tid]     = inno[b0*8 + tid];
    __syncthreads();

    const int wave = tid >> 6;
    const int l15  = tid & 15;
    const int quad = (tid >> 4) & 3;
    const f32x4 zero4 = {0.f, 0.f, 0.f, 0.f};

    // ---- GEMM1: gx = X @ W_ih^T, 4 per-tile passes (acc 24 regs/pass) ----
    #pragma unroll 1
    for (int it = 0; it < 4; ++it) {
        f32x4 aR[2], aZ[2], aN[2];
        #pragma unroll
        for (int m = 0; m < 2; ++m) { aR[m] = zero4; aZ[m] = zero4; aN[m] = zero4; }

        const int nrow = (wave + 4*it)*16 + l15;     // it=3,wave=3 -> zero-padded rows
        const __hip_bfloat16* wr = Wihb + nrow*256;
        #pragma unroll
        for (int ks = 0; ks < 8; ++ks) {
            const int ko = ks*32 + quad*8;
            bf16x8 a0 = *(const bf16x8*)&Xs[l15*XS_STRIDE + ko];
            bf16x8 a1 = *(const bf16x8*)&Xs[(16 + l15)*XS_STRIDE + ko];
            bf16x8 br = *(const bf16x8*)&wr[ko];
            bf16x8 bz = *(const bf16x8*)&wr[240*256 + ko];
            bf16x8 bn = *(const bf16x8*)&wr[480*256 + ko];
            aR[0] = MFMA16(a0, br, aR[0]);
            aR[1] = MFMA16(a1, br, aR[1]);
            aZ[0] = MFMA16(a0, bz, aZ[0]);
            aZ[1] = MFMA16(a1, bz, aZ[1]);
            aN[0] = MFMA16(a0, bn, aN[0]);
            aN[1] = MFMA16(a1, bn, aN[1]);
        }
        // GRU nonlinearity -> Hs (bf16)
        const int t = wave + 4*it;
        if (t < 15) {
            const int h = t*16 + l15;
            const float add_r = ghb[h],       add_z = ghb[240 + h];
            const float add_n = ghb[480 + h], mul_n = ghb[720 + h];
            const float hi = h_init[h];
            #pragma unroll
            for (int m = 0; m < 2; ++m)
                #pragma unroll
                for (int r = 0; r < 4; ++r) {
                    const int row = m*16 + quad*4 + r;
                    float rg = 1.0f/(1.0f + expf(-(aR[m][r] + add_r)));
                    float zg = 1.0f/(1.0f + expf(-(aZ[m][r] + add_z)));
                    float ng = tanhf(aN[m][r] + add_n + rg*mul_n);
                    Hs[row*XS_STRIDE + h] = __float2bfloat16((1.0f - zg)*ng + zg*hi);
                }
        }
    }
    __syncthreads();

    // ---- GEMM2: o1 = relu(H @ W_out1^T + b)*mask2  (N=512, 8 tiles/wave) ----
    {
        f32x4 acc2[8][2];
        #pragma unroll
        for (int it = 0; it < 8; it++) { acc2[it][0] = zero4; acc2[it][1] = zero4; }

        #pragma unroll
        for (int ks = 0; ks < 8; ++ks) {
            const int ko = ks*32 + quad*8;
            bf16x8 a0 = *(const bf16x8*)&Hs[l15*XS_STRIDE + ko];
            bf16x8 a1 = *(const bf16x8*)&Hs[(16 + l15)*XS_STRIDE + ko];
            #pragma unroll
            for (int it = 0; it < 8; ++it) {
                const int n = (wave*8 + it)*16 + l15;
                bf16x8 b = *(const bf16x8*)&Wo1b[n*256 + ko];
                acc2[it][0] = MFMA16(a0, b, acc2[it][0]);
                acc2[it][1] = MFMA16(a1, b, acc2[it][1]);
            }
        }
        __syncthreads();   // Hs/Xs now dead; O1s may overlay them
        const float inv35 = 1.0f/0.35f;
        #pragma unroll
        for (int it = 0; it < 8; ++it) {
            const int n = (wave*8 + it)*16 + l15;
            const float bb = b_out1[n];
            const int wbase = wave*4 + (it >> 1);      // (n>>5)
            const int bitpos = ((it & 1) << 4) | l15;  // (n&31)
            #pragma unroll
            for (int m = 0; m < 2; ++m)
                #pragma unroll
                for (int r = 0; r < 4; ++r) {
                    const int row = m*16 + quad*4 + r;
                    unsigned int mw = Mbits[row*16 + wbase];
                    float o = fmaxf(acc2[it][m][r] + bb, 0.0f);
                    o = ((mw >> bitpos) & 1u) ? o*inv35 : 0.0f;
                    O1s[row*O1_STRIDE + n] = __float2bfloat16(o);
                }
        }
    }
    __syncthreads();

    // ---- GEMM3: K = o1 @ W_out2^T + b; corr = K.inno; ensemble write ----
    {
        f32x4 acc3[2][2];
        #pragma unroll
        for (int it = 0; it < 2; ++it) {
            const int n = (wave*2 + it)*16 + l15;
            const float bo = b_out2[n];
            f32x4 v = {bo, bo, bo, bo};
            acc3[it][0] = v; acc3[it][1] = v;
        }
        #pragma unroll
        for (int ks = 0; ks < 16; ++ks) {
            const int ko = ks*32 + quad*8;
            bf16x8 a0 = *(const bf16x8*)&O1s[l15*O1_STRIDE + ko];
            bf16x8 a1 = *(const bf16x8*)&O1s[(16 + l15)*O1_STRIDE + ko];
            #pragma unroll
            for (int it = 0; it < 2; ++it) {
                const int n = (wave*2 + it)*16 + l15;
                bf16x8 b = *(const bf16x8*)&Wo2b[n*512 + ko];
                acc3[it][0] = MFMA16(a0, b, acc3[it][0]);
                acc3[it][1] = MFMA16(a1, b, acc3[it][1]);
            }
        }
        #pragma unroll
        for (int it = 0; it < 2; ++it) {
            const int n = (wave*2 + it)*16 + l15;
            const int s = n >> 3, o = n & 7;
            #pragma unroll
            for (int m = 0; m < 2; ++m)
                #pragma unroll
                for (int r = 0; r < 4; ++r) {
                    const int row = m*16 + quad*4 + r;
                    float v = acc3[it][m][r] * InnoS[row*8 + o];
                    v += __shfl_xor(v, 1);
                    v += __shfl_xor(v, 2);
                    v += __shfl_xor(v, 4);
                    if (o == 0)
                        ens[((b0 + row)*J_DIM + j)*16 + s] = XPs[row*16 + s] + v;
                }
        }
    }
}

// ---------------------------------------------------------------------------
// final: mean/var(ddof=1) over J per (b,s) + reg scalar
// ---------------------------------------------------------------------------
__global__ void k_final(const float* __restrict__ ens, float* __restrict__ out)
{
    int t = blockIdx.x * 256 + threadIdx.x;   // 65536 = B*S
    int b = t >> 4, s = t & 15;
    float v[32];
    #pragma unroll
    for (int jj = 0; jj < 32; jj++) v[jj] = ens[(b*32 + jj)*16 + s];
    float m = 0.f;
    #pragma unroll
    for (int jj = 0; jj < 32; jj++) m += v[jj];
    m *= (1.0f/32.0f);
    float var = 0.f;
    #pragma unroll
    for (int jj = 0; jj < 32; jj++) { float d = v[jj] - m; var = fmaf(d, d, var); }
    var *= (1.0f/31.0f);
    out[OUT_X + t] = m;
    out[OUT_P + t] = var;
    if (t == 0) out[OUT_REG] = 1.3405938195945778f;  // ln2 + H(0.65)
}

// ---------------------------------------------------------------------------
extern "C" void kernel_launch(void* const* d_in, const int* in_sizes, int n_in,
                              void* d_out, int out_size, void* d_ws, size_t ws_size,
                              hipStream_t stream)
{
    (void)in_sizes; (void)n_in; (void)out_size; (void)ws_size;
    const float* y_t    = (const float*)d_in[0];
    const float* xprev  = (const float*)d_in[1];
    const float* F      = (const float*)d_in[2];
    const float* Hm     = (const float*)d_in[3];
    const float* Wfc    = (const float*)d_in[4];
    const float* bfc    = (const float*)d_in[5];
    const float* W_ih   = (const float*)d_in[6];
    const float* W_hh   = (const float*)d_in[7];
    const float* b_ih   = (const float*)d_in[8];
    const float* b_hh   = (const float*)d_in[9];
    const float* W_o1   = (const float*)d_in[10];
    const float* b_o1   = (const float*)d_in[11];
    const float* W_o2   = (const float*)d_in[12];
    const float* b_o2   = (const float*)d_in[13];
    const float* h_init = (const float*)d_in[14];
    const float* u1     = (const float*)d_in[15];
    const float* u2     = (const float*)d_in[16];

    float* out = (float*)d_out;
    float* ws  = (float*)d_ws;
    float* x_pred = ws + WS_XPRED;
    float* inno   = ws + WS_INNO;
    float* feats  = ws + WS_FEATS;
    float* x_in0  = ws + WS_XIN0;
    float* ghb    = ws + WS_GH;
    __hip_bfloat16* Wihb = (__hip_bfloat16*)((char*)d_ws + WS_WB_OFF);
    __hip_bfloat16* Wo1b = Wihb + 768*256;
    __hip_bfloat16* Wo2b = Wo1b + 512*256;
    float* ens    = out + OUT_ENS;

    k_aux_pre<<<dim3(1552), dim3(256), 0, stream>>>(W_ih, W_hh, b_ih, b_hh, h_init,
                                                    W_o1, W_o2, Wihb, Wo1b, Wo2b, ghb,
                                                    y_t, xprev, F, Hm, x_pred, inno, feats);
    k_pre_b<<<dim3(3840), dim3(256), 0, stream>>>(feats, Wfc, bfc, x_in0);
    k_main<<<dim3(4096), dim3(256), 0, stream>>>(x_in0, u1, u2, Wihb, ghb, h_init,
                                                 Wo1b, b_o1, Wo2b, b_o2,
                                                 x_pred, inno, ens);
    k_final<<<dim3(256), dim3(256), 0, stream>>>(ens, out);
}

// Round 4
// 770.258 us; speedup vs baseline: 1.1292x; 1.0956x over previous
//
#include <hip/hip_runtime.h>
#include <hip/hip_bf16.h>
#include <math.h>

#define S_DIM 16
#define O_DIM 8
#define J_DIM 32
#define B_DIM 4096
#define HID 240
#define OHID 512

typedef __attribute__((ext_vector_type(8))) short bf16x8;
typedef __attribute__((ext_vector_type(4))) float f32x4;
#define MFMA16(a,b,c) __builtin_amdgcn_mfma_f32_16x16x32_bf16((a),(b),(c),0,0,0)

static __device__ __forceinline__ float fast_rcp(float x) { return __builtin_amdgcn_rcpf(x); }
static __device__ __forceinline__ float fast_sigmoid(float x) {
    return fast_rcp(1.0f + __expf(-x));           // ~3 VALU ops vs ~15 libm
}
static __device__ __forceinline__ float fast_tanh(float x) {
    float t = __expf(2.0f * x);                   // inf-safe: rcp(inf)=0 -> 1; t=0 -> -1
    return 1.0f - 2.0f * fast_rcp(t + 1.0f);
}

// ws layout (float offsets for fp32 part)
#define WS_XPRED   0                                  // [B,16]
#define WS_INNO    (WS_XPRED + B_DIM*S_DIM)           // [B,8]
#define WS_FEATS   (WS_INNO + B_DIM*O_DIM)            // [B,48]
#define WS_XIN0    (WS_FEATS + B_DIM*48)              // [B,240]
#define WS_GH      (WS_XIN0 + B_DIM*HID)              // [960]
#define WS_WB_OFF  ((WS_GH + 960) * 4)                // byte offset: bf16 weights
// bf16 weights: Wihb[768][256], Wo1b[512][256], Wo2b[128][512]

// out layout (float offsets)
#define OUT_X      0
#define OUT_P      (B_DIM*S_DIM)                      // 65536
#define OUT_REG    (2*B_DIM*S_DIM)                    // 131072
#define OUT_ENS    (2*B_DIM*S_DIM + 1)                // 131073

// ---------------------------------------------------------------------------
// aux+pre_a merged: blocks [0,1536) cast weights to bf16 (K-padded) + GRU gh
// precompute; blocks [1536,1552) do the Kalman prefix per b.
// ---------------------------------------------------------------------------
__global__ void k_aux_pre(const float* __restrict__ W_ih, const float* __restrict__ W_hh,
                          const float* __restrict__ b_ih, const float* __restrict__ b_hh,
                          const float* __restrict__ h_init,
                          const float* __restrict__ W_o1, const float* __restrict__ W_o2,
                          __hip_bfloat16* __restrict__ Wihb, __hip_bfloat16* __restrict__ Wo1b,
                          __hip_bfloat16* __restrict__ Wo2b, float* __restrict__ ghb,
                          const float* __restrict__ y, const float* __restrict__ xprev,
                          const float* __restrict__ F, const float* __restrict__ Hm,
                          float* __restrict__ x_pred, float* __restrict__ inno,
                          float* __restrict__ feats)
{
    __shared__ float sF[256], sH[128];
    const int tid = threadIdx.x;
    if (blockIdx.x < 1536) {
        int t = blockIdx.x * 256 + tid;
        if (t < 768*256) {
            int n = t >> 8, k = t & 255;
            float v = (n < 720 && k < 240) ? W_ih[n*240 + k] : 0.0f;
            Wihb[t] = __float2bfloat16(v);
        } else if (t < 768*256 + 512*256) {
            int u = t - 768*256;
            int n = u >> 8, k = u & 255;
            float v = (k < 240) ? W_o1[n*240 + k] : 0.0f;
            Wo1b[u] = __float2bfloat16(v);
        } else if (t < 768*256 + 512*256 + 128*512) {
            int u = t - 768*256 - 512*256;
            Wo2b[u] = __float2bfloat16(W_o2[u]);
        }
        if (t < 720) {
            float a = b_hh[t];
            const float* wr = W_hh + t*240;
            for (int k = 0; k < 240; k++) a = fmaf(h_init[k], wr[k], a);
            if (t < 480) {
                ghb[t] = b_ih[t] + a;            // r/z gates: bias fully folded
            } else {
                ghb[t] = b_ih[t];                // n gate: additive part
                ghb[t + 240] = a;                // n gate: part multiplied by r
            }
        }
        return;
    }
    // ---- pre_a part ----
    sF[tid] = F[tid];
    if (tid < 128) sH[tid] = Hm[tid];
    __syncthreads();
    int b = (blockIdx.x - 1536) * 256 + tid;
    float xf[16], xp[16], inn[8];
    #pragma unroll
    for (int s = 0; s < 16; s++) xf[s] = xprev[b*16 + s];
    #pragma unroll
    for (int s = 0; s < 16; s++) {
        float a = 0.f;
        #pragma unroll
        for (int k = 0; k < 16; k++) a = fmaf(xf[k], sF[s*16 + k], a);
        xp[s] = a;
    }
    #pragma unroll
    for (int o = 0; o < 8; o++) {
        float a = 0.f;
        #pragma unroll
        for (int k = 0; k < 16; k++) a = fmaf(xp[k], sH[o*16 + k], a);
        inn[o] = y[b*8 + o] - a;
    }
    #pragma unroll
    for (int s = 0; s < 16; s++) x_pred[b*16 + s] = xp[s];
    #pragma unroll
    for (int o = 0; o < 8; o++) inno[b*8 + o] = inn[o];
    float* fb = feats + b*48;
    #pragma unroll
    for (int s = 0; s < 16; s++) fb[s] = xf[s] - xp[s];
    #pragma unroll
    for (int o = 0; o < 8; o++) fb[16 + o] = inn[o];
    #pragma unroll
    for (int s = 0; s < 16; s++) fb[24 + s] = 0.f;
    #pragma unroll
    for (int o = 0; o < 8; o++) fb[40 + o] = inn[o];
}

// ---------------------------------------------------------------------------
// pre_b: x_in0 = relu(feats @ W_fc^T + b_fc)
// ---------------------------------------------------------------------------
__global__ void k_pre_b(const float* __restrict__ feats, const float* __restrict__ Wfc,
                        const float* __restrict__ bfc, float* __restrict__ x_in0)
{
    int t = blockIdx.x * 256 + threadIdx.x;
    int b = t / 240, h = t - b*240;
    const float* fb = feats + b*48;
    const float* wr = Wfc + h*48;
    float a = bfc[h];
    #pragma unroll
    for (int k = 0; k < 48; k += 4) {
        const float4 f4 = *(const float4*)&fb[k];
        const float4 w4 = *(const float4*)&wr[k];
        a = fmaf(f4.x, w4.x, fmaf(f4.y, w4.y, fmaf(f4.z, w4.z, fmaf(f4.w, w4.w, a))));
    }
    x_in0[t] = fmaxf(a, 0.f);
}

// ---------------------------------------------------------------------------
// main: bf16 MFMA fused chain. M=64 rows/block (64 b-rows x 1 j), 512 thr
// (8 waves), grid 2048. Each 16B weight load feeds 4 MFMAs (was 2); total
// L2 weight traffic halves -> less exposed load latency per unit work.
// LDS 76KB -> 2 blocks/CU = 16 waves/CU (4/SIMD: 12 MFMA x 4 waves = 240cy
// per 3-load batch > ~200cy L2 latency -> covered). GRU uses native exp/rcp.
// ---------------------------------------------------------------------------
#define XS_STRIDE 264   // 240+24 pad bf16
#define O1_STRIDE 520   // 512+8 pad bf16

// LDS byte map:
//   [0,33792)      Xs  [64][264] bf16
//   [33792,67584)  Hs  [64][264] bf16
//   [0,66560)      O1s [64][520] bf16   (overlays Xs+Hs after GEMM2-acc barrier)
//   [67584,71680)  Mbits[1024] u32      (u2 keep-mask, bit f = row*512+n)
//   [71680,75776)  XPs [64][16] f32
//   [75776,77824)  InnoS [64][8] f32
__global__ __launch_bounds__(512, 2) void k_main(
    const float* __restrict__ x_in0, const float* __restrict__ u1,
    const float* __restrict__ u2,
    const __hip_bfloat16* __restrict__ Wihb, const float* __restrict__ ghb,
    const float* __restrict__ h_init,
    const __hip_bfloat16* __restrict__ Wo1b, const float* __restrict__ b_out1,
    const __hip_bfloat16* __restrict__ Wo2b, const float* __restrict__ b_out2,
    const float* __restrict__ x_pred, const float* __restrict__ inno,
    float* __restrict__ ens)
{
    __shared__ __align__(16) char smem[77824];
    __hip_bfloat16* Xs  = (__hip_bfloat16*)smem;            // [64][264]
    __hip_bfloat16* Hs  = (__hip_bfloat16*)(smem + 33792);  // [64][264]
    __hip_bfloat16* O1s = (__hip_bfloat16*)smem;            // [64][520], overlays Xs+Hs
    unsigned int* Mbits = (unsigned int*)(smem + 67584);    // [1024]
    float* XPs   = (float*)(smem + 71680);                  // [64][16]
    float* InnoS = (float*)(smem + 75776);                  // [64][8]

    const int tid = threadIdx.x;
    const int j  = blockIdx.x >> 6;          // 64 blocks per j
    const int b0 = (blockIdx.x & 63) << 6;   // 64 b-rows per block

    // ---- phase 0a: u2 keep-mask -> Mbits (coalesced float4 over contiguous 128KB) ----
    {
        const float4* u2t = (const float4*)(u2 + ((size_t)(j*B_DIM + b0) << 9));
        const int sh = (tid & 7) * 4;
        #pragma unroll
        for (int it = 0; it < 16; ++it) {
            float4 q = u2t[tid + 512*it];
            unsigned int nib = (q.x > 0.65f ? 1u : 0u) | (q.y > 0.65f ? 2u : 0u)
                             | (q.z > 0.65f ? 4u : 0u) | (q.w > 0.65f ? 8u : 0u);
            unsigned int v = nib << sh;
            v |= __shfl_xor(v, 1);
            v |= __shfl_xor(v, 2);
            v |= __shfl_xor(v, 4);
            if ((tid & 7) == 0) Mbits[(tid >> 3) + 64*it] = v;
        }
    }

    // ---- phase 0b: stage masked bf16 X tile (float4, contiguous 60KB tiles) ----
    {
        const float4* xt = (const float4*)(x_in0 + b0*240);
        const float4* ut = (const float4*)(u1 + (size_t)(j*B_DIM + b0)*240);
        #pragma unroll
        for (int it = 0; it < 8; ++it) {
            int idx = tid + 512*it;
            if (idx < 3840) {
                float4 xv = xt[idx];
                float4 uv = ut[idx];
                int i = idx / 60;                 // 60 float4 per row (240 floats)
                int h = (idx - i*60) * 4;         // multiple of 4
                __align__(8) __hip_bfloat16 o[4];
                o[0] = __float2bfloat16(uv.x > 0.5f ? 2.0f*xv.x : 0.0f);
                o[1] = __float2bfloat16(uv.y > 0.5f ? 2.0f*xv.y : 0.0f);
                o[2] = __float2bfloat16(uv.z > 0.5f ? 2.0f*xv.z : 0.0f);
                o[3] = __float2bfloat16(uv.w > 0.5f ? 2.0f*xv.w : 0.0f);
                *(uint2*)&Xs[i*XS_STRIDE + h] = *(const uint2*)o;
            }
        }
    }
    // zero K-pad cols [240,256) for Xs and Hs (MFMA reads up to col 256)
    if (tid < 256) {
        int row = tid >> 2, c = 240 + ((tid & 3) << 2);
        uint2 z = {0u, 0u};
        *(uint2*)&Xs[row*XS_STRIDE + c] = z;
        *(uint2*)&Hs[row*XS_STRIDE + c] = z;
    }
    XPs[tid]       = x_pred[b0*16 + tid];
    XPs[tid + 512] = x_pred[b0*16 + tid + 512];
    InnoS[tid & 511] = inno[b0*8 + (tid & 511)];   // 512 values
    __syncthreads();

    const int wave = tid >> 6;
    const int l15  = tid & 15;
    const int quad = (tid >> 4) & 3;
    const f32x4 zero4 = {0.f, 0.f, 0.f, 0.f};

    // ---- GEMM1: gx = X @ W_ih^T, 15 h-tiles over 8 waves (2 slots) ----
    #pragma unroll 1
    for (int sl = 0; sl < 2; ++sl) {
        const int t = wave + 8*sl;
        if (t < 15) {                        // wave 7 idle on sl=1 (wave-uniform, no barrier inside)
            f32x4 aR[4], aZ[4], aN[4];
            #pragma unroll
            for (int m = 0; m < 4; ++m) { aR[m] = zero4; aZ[m] = zero4; aN[m] = zero4; }

            const int nrow = t*16 + l15;
            const __hip_bfloat16* wr = Wihb + nrow*256;
            #pragma unroll
            for (int ks = 0; ks < 8; ++ks) {
                const int ko = ks*32 + quad*8;
                bf16x8 a[4];
                #pragma unroll
                for (int m = 0; m < 4; ++m)
                    a[m] = *(const bf16x8*)&Xs[(m*16 + l15)*XS_STRIDE + ko];
                bf16x8 br = *(const bf16x8*)&wr[ko];
                bf16x8 bz = *(const bf16x8*)&wr[240*256 + ko];
                bf16x8 bn = *(const bf16x8*)&wr[480*256 + ko];
                #pragma unroll
                for (int m = 0; m < 4; ++m) {
                    aR[m] = MFMA16(a[m], br, aR[m]);
                    aZ[m] = MFMA16(a[m], bz, aZ[m]);
                    aN[m] = MFMA16(a[m], bn, aN[m]);
                }
            }
            // GRU nonlinearity -> Hs (bf16), native exp/rcp
            const int h = t*16 + l15;
            const float add_r = ghb[h],       add_z = ghb[240 + h];
            const float add_n = ghb[480 + h], mul_n = ghb[720 + h];
            const float hi = h_init[h];
            #pragma unroll
            for (int m = 0; m < 4; ++m)
                #pragma unroll
                for (int r = 0; r < 4; ++r) {
                    const int row = m*16 + quad*4 + r;
                    float rg = fast_sigmoid(aR[m][r] + add_r);
                    float zg = fast_sigmoid(aZ[m][r] + add_z);
                    float ng = fast_tanh(aN[m][r] + add_n + rg*mul_n);
                    Hs[row*XS_STRIDE + h] = __float2bfloat16(fmaf(zg, hi - ng, ng));
                }
        }
    }
    __syncthreads();

    // ---- GEMM2: o1 = relu(H @ W_out1^T + b)*mask2  (N=512, 4 tiles/wave) ----
    {
        f32x4 acc2[4][4];
        #pragma unroll
        for (int it = 0; it < 4; ++it)
            #pragma unroll
            for (int m = 0; m < 4; ++m) acc2[it][m] = zero4;

        #pragma unroll
        for (int ks = 0; ks < 8; ++ks) {
            const int ko = ks*32 + quad*8;
            bf16x8 a[4];
            #pragma unroll
            for (int m = 0; m < 4; ++m)
                a[m] = *(const bf16x8*)&Hs[(m*16 + l15)*XS_STRIDE + ko];
            #pragma unroll
            for (int it = 0; it < 4; ++it) {
                const int n = (wave*4 + it)*16 + l15;
                bf16x8 b = *(const bf16x8*)&Wo1b[n*256 + ko];
                #pragma unroll
                for (int m = 0; m < 4; ++m)
                    acc2[it][m] = MFMA16(a[m], b, acc2[it][m]);
            }
        }
        __syncthreads();   // Hs/Xs now dead; O1s may overlay them
        const float inv35 = 1.0f/0.35f;
        #pragma unroll
        for (int it = 0; it < 4; ++it) {
            const int n = (wave*4 + it)*16 + l15;
            const float bb = b_out1[n];
            const int wbase = (wave*4 + it) >> 1;      // n>>5
            const int bitpos = ((it & 1) << 4) | l15;  // n&31
            #pragma unroll
            for (int m = 0; m < 4; ++m)
                #pragma unroll
                for (int r = 0; r < 4; ++r) {
                    const int row = m*16 + quad*4 + r;
                    unsigned int mw = Mbits[row*16 + wbase];
                    float o = fmaxf(acc2[it][m][r] + bb, 0.0f);
                    o = ((mw >> bitpos) & 1u) ? o*inv35 : 0.0f;
                    O1s[row*O1_STRIDE + n] = __float2bfloat16(o);
                }
        }
    }
    __syncthreads();

    // ---- GEMM3: K = o1 @ W_out2^T + b; corr = K.inno; ensemble write ----
    {
        const int n = wave*16 + l15;          // 8 waves x 16 = N=128
        const float bo = b_out2[n];
        f32x4 acc3[4];
        #pragma unroll
        for (int m = 0; m < 4; ++m) { f32x4 v = {bo, bo, bo, bo}; acc3[m] = v; }

        #pragma unroll
        for (int ks = 0; ks < 16; ++ks) {
            const int ko = ks*32 + quad*8;
            bf16x8 b = *(const bf16x8*)&Wo2b[n*512 + ko];
            #pragma unroll
            for (int m = 0; m < 4; ++m) {
                bf16x8 a = *(const bf16x8*)&O1s[(m*16 + l15)*O1_STRIDE + ko];
                acc3[m] = MFMA16(a, b, acc3[m]);
            }
        }
        const int s = n >> 3, o = n & 7;
        #pragma unroll
        for (int m = 0; m < 4; ++m)
            #pragma unroll
            for (int r = 0; r < 4; ++r) {
                const int row = m*16 + quad*4 + r;
                float v = acc3[m][r] * InnoS[row*8 + o];
                v += __shfl_xor(v, 1);
                v += __shfl_xor(v, 2);
                v += __shfl_xor(v, 4);
                if (o == 0)
                    ens[((b0 + row)*J_DIM + j)*16 + s] = XPs[row*16 + s] + v;
            }
    }
}

// ---------------------------------------------------------------------------
// final: mean/var(ddof=1) over J per (b,s) + reg scalar
// ---------------------------------------------------------------------------
__global__ void k_final(const float* __restrict__ ens, float* __restrict__ out)
{
    int t = blockIdx.x * 256 + threadIdx.x;   // 65536 = B*S
    int b = t >> 4, s = t & 15;
    float v[32];
    #pragma unroll
    for (int jj = 0; jj < 32; jj++) v[jj] = ens[(b*32 + jj)*16 + s];
    float m = 0.f;
    #pragma unroll
    for (int jj = 0; jj < 32; jj++) m += v[jj];
    m *= (1.0f/32.0f);
    float var = 0.f;
    #pragma unroll
    for (int jj = 0; jj < 32; jj++) { float d = v[jj] - m; var = fmaf(d, d, var); }
    var *= (1.0f/31.0f);
    out[OUT_X + t] = m;
    out[OUT_P + t] = var;
    if (t == 0) out[OUT_REG] = 1.3405938195945778f;  // ln2 + H(0.65)
}

// ---------------------------------------------------------------------------
extern "C" void kernel_launch(void* const* d_in, const int* in_sizes, int n_in,
                              void* d_out, int out_size, void* d_ws, size_t ws_size,
                              hipStream_t stream)
{
    (void)in_sizes; (void)n_in; (void)out_size; (void)ws_size;
    const float* y_t    = (const float*)d_in[0];
    const float* xprev  = (const float*)d_in[1];
    const float* F      = (const float*)d_in[2];
    const float* Hm     = (const float*)d_in[3];
    const float* Wfc    = (const float*)d_in[4];
    const float* bfc    = (const float*)d_in[5];
    const float* W_ih   = (const float*)d_in[6];
    const float* W_hh   = (const float*)d_in[7];
    const float* b_ih   = (const float*)d_in[8];
    const float* b_hh   = (const float*)d_in[9];
    const float* W_o1   = (const float*)d_in[10];
    const float* b_o1   = (const float*)d_in[11];
    const float* W_o2   = (const float*)d_in[12];
    const float* b_o2   = (const float*)d_in[13];
    const float* h_init = (const float*)d_in[14];
    const float* u1     = (const float*)d_in[15];
    const float* u2     = (const float*)d_in[16];

    float* out = (float*)d_out;
    float* ws  = (float*)d_ws;
    float* x_pred = ws + WS_XPRED;
    float* inno   = ws + WS_INNO;
    float* feats  = ws + WS_FEATS;
    float* x_in0  = ws + WS_XIN0;
    float* ghb    = ws + WS_GH;
    __hip_bfloat16* Wihb = (__hip_bfloat16*)((char*)d_ws + WS_WB_OFF);
    __hip_bfloat16* Wo1b = Wihb + 768*256;
    __hip_bfloat16* Wo2b = Wo1b + 512*256;
    float* ens    = out + OUT_ENS;

    k_aux_pre<<<dim3(1552), dim3(256), 0, stream>>>(W_ih, W_hh, b_ih, b_hh, h_init,
                                                    W_o1, W_o2, Wihb, Wo1b, Wo2b, ghb,
                                                    y_t, xprev, F, Hm, x_pred, inno, feats);
    k_pre_b<<<dim3(3840), dim3(256), 0, stream>>>(feats, Wfc, bfc, x_in0);
    k_main<<<dim3(2048), dim3(512), 0, stream>>>(x_in0, u1, u2, Wihb, ghb, h_init,
                                                 Wo1b, b_o1, Wo2b, b_o2,
                                                 x_pred, inno, ens);
    k_final<<<dim3(256), dim3(256), 0, stream>>>(ens, out);
}

// Round 5
// 753.817 us; speedup vs baseline: 1.1538x; 1.0218x over previous
//
#include <hip/hip_runtime.h>
#include <hip/hip_bf16.h>
#include <math.h>

#define S_DIM 16
#define O_DIM 8
#define J_DIM 32
#define B_DIM 4096
#define HID 240
#define OHID 512

typedef __attribute__((ext_vector_type(8))) short bf16x8;
typedef __attribute__((ext_vector_type(4))) float f32x4;
#define MFMA16(a,b,c) __builtin_amdgcn_mfma_f32_16x16x32_bf16((a),(b),(c),0,0,0)

static __device__ __forceinline__ float fast_rcp(float x) { return __builtin_amdgcn_rcpf(x); }
static __device__ __forceinline__ float fast_sigmoid(float x) {
    return fast_rcp(1.0f + __expf(-x));
}
static __device__ __forceinline__ float fast_tanh(float x) {
    float t = __expf(2.0f * x);                   // inf-safe: rcp(inf)=0 -> 1; t=0 -> -1
    return 1.0f - 2.0f * fast_rcp(t + 1.0f);
}

// ws layout (float offsets for fp32 part)
#define WS_XPRED   0                                  // [B,16]
#define WS_INNO    (WS_XPRED + B_DIM*S_DIM)           // [B,8]
#define WS_FEATS   (WS_INNO + B_DIM*O_DIM)            // [B,48]
#define WS_XIN0    (WS_FEATS + B_DIM*48)              // [B,240]
#define WS_GH      (WS_XIN0 + B_DIM*HID)              // [960]
#define WS_WB_OFF  ((WS_GH + 960) * 4)                // byte offset: bf16 weights
// bf16 weights (fragment-major): Wihb[48 tiles][8 ks][4 q][16 l][8]  (=768x256)
//                                Wo1b[32 tiles][8 ks][4 q][16 l][8]  (=512x256)
//                                Wo2b[ 8 tiles][16 ks][4 q][16 l][8] (=128x512)
// flat idx = (((tile*KS + ks)*4 + q)*16 + l)*8 + e ; row=tile*16+l, col=ks*32+q*8+e
// -> a wave's fragment load (lanes = q*16+l) reads 1024 CONTIGUOUS bytes.

// out layout (float offsets)
#define OUT_X      0
#define OUT_P      (B_DIM*S_DIM)                      // 65536
#define OUT_REG    (2*B_DIM*S_DIM)                    // 131072
#define OUT_ENS    (2*B_DIM*S_DIM + 1)                // 131073

// ---------------------------------------------------------------------------
// aux+pre_a merged: blocks [0,1536) build fragment-major bf16 weights + GRU gh
// precompute; blocks [1536,1552) do the Kalman prefix per b.
// ---------------------------------------------------------------------------
__global__ void k_aux_pre(const float* __restrict__ W_ih, const float* __restrict__ W_hh,
                          const float* __restrict__ b_ih, const float* __restrict__ b_hh,
                          const float* __restrict__ h_init,
                          const float* __restrict__ W_o1, const float* __restrict__ W_o2,
                          __hip_bfloat16* __restrict__ Wihb, __hip_bfloat16* __restrict__ Wo1b,
                          __hip_bfloat16* __restrict__ Wo2b, float* __restrict__ ghb,
                          const float* __restrict__ y, const float* __restrict__ xprev,
                          const float* __restrict__ F, const float* __restrict__ Hm,
                          float* __restrict__ x_pred, float* __restrict__ inno,
                          float* __restrict__ feats)
{
    __shared__ float sF[256], sH[128];
    const int tid = threadIdx.x;
    if (blockIdx.x < 1536) {
        int t = blockIdx.x * 256 + tid;
        if (t < 196608) {                               // Wihb (768x256)
            int e = t & 7, l = (t >> 3) & 15, q = (t >> 7) & 3;
            int ks = (t >> 9) & 7, tile = t >> 12;
            int row = tile*16 + l, col = ks*32 + q*8 + e;
            float v = (row < 720 && col < 240) ? W_ih[row*240 + col] : 0.0f;
            Wihb[t] = __float2bfloat16(v);
        } else if (t < 196608 + 131072) {               // Wo1b (512x256)
            int u = t - 196608;
            int e = u & 7, l = (u >> 3) & 15, q = (u >> 7) & 3;
            int ks = (u >> 9) & 7, tile = u >> 12;
            int row = tile*16 + l, col = ks*32 + q*8 + e;
            float v = (col < 240) ? W_o1[row*240 + col] : 0.0f;
            Wo1b[u] = __float2bfloat16(v);
        } else if (t < 393216) {                        // Wo2b (128x512)
            int u = t - 327680;
            int e = u & 7, l = (u >> 3) & 15, q = (u >> 7) & 3;
            int ks = (u >> 9) & 15, tile = u >> 13;
            int row = tile*16 + l, col = ks*32 + q*8 + e;
            Wo2b[u] = __float2bfloat16(W_o2[row*512 + col]);
        }
        if (t < 720) {
            float a = b_hh[t];
            const float* wr = W_hh + t*240;
            for (int k = 0; k < 240; k++) a = fmaf(h_init[k], wr[k], a);
            if (t < 480) {
                ghb[t] = b_ih[t] + a;            // r/z gates: bias fully folded
            } else {
                ghb[t] = b_ih[t];                // n gate: additive part
                ghb[t + 240] = a;                // n gate: part multiplied by r
            }
        }
        return;
    }
    // ---- pre_a part ----
    sF[tid] = F[tid];
    if (tid < 128) sH[tid] = Hm[tid];
    __syncthreads();
    int b = (blockIdx.x - 1536) * 256 + tid;
    float xf[16], xp[16], inn[8];
    #pragma unroll
    for (int s = 0; s < 16; s++) xf[s] = xprev[b*16 + s];
    #pragma unroll
    for (int s = 0; s < 16; s++) {
        float a = 0.f;
        #pragma unroll
        for (int k = 0; k < 16; k++) a = fmaf(xf[k], sF[s*16 + k], a);
        xp[s] = a;
    }
    #pragma unroll
    for (int o = 0; o < 8; o++) {
        float a = 0.f;
        #pragma unroll
        for (int k = 0; k < 16; k++) a = fmaf(xp[k], sH[o*16 + k], a);
        inn[o] = y[b*8 + o] - a;
    }
    #pragma unroll
    for (int s = 0; s < 16; s++) x_pred[b*16 + s] = xp[s];
    #pragma unroll
    for (int o = 0; o < 8; o++) inno[b*8 + o] = inn[o];
    float* fb = feats + b*48;
    #pragma unroll
    for (int s = 0; s < 16; s++) fb[s] = xf[s] - xp[s];
    #pragma unroll
    for (int o = 0; o < 8; o++) fb[16 + o] = inn[o];
    #pragma unroll
    for (int s = 0; s < 16; s++) fb[24 + s] = 0.f;
    #pragma unroll
    for (int o = 0; o < 8; o++) fb[40 + o] = inn[o];
}

// ---------------------------------------------------------------------------
// pre_b: x_in0 = relu(feats @ W_fc^T + b_fc)
// ---------------------------------------------------------------------------
__global__ void k_pre_b(const float* __restrict__ feats, const float* __restrict__ Wfc,
                        const float* __restrict__ bfc, float* __restrict__ x_in0)
{
    int t = blockIdx.x * 256 + threadIdx.x;
    int b = t / 240, h = t - b*240;
    const float* fb = feats + b*48;
    const float* wr = Wfc + h*48;
    float a = bfc[h];
    #pragma unroll
    for (int k = 0; k < 48; k += 4) {
        const float4 f4 = *(const float4*)&fb[k];
        const float4 w4 = *(const float4*)&wr[k];
        a = fmaf(f4.x, w4.x, fmaf(f4.y, w4.y, fmaf(f4.z, w4.z, fmaf(f4.w, w4.w, a))));
    }
    x_in0[t] = fmaxf(a, 0.f);
}

// ---------------------------------------------------------------------------
// main: bf16 MFMA fused chain. M=64 rows/block, 512 thr (8 waves), grid 2048.
// Weights in fragment-major layout: each wave's 16B/lane fragment load is a
// single 1KB contiguous burst (was 64 scattered 512B-strided lines -> the
// dominant exposed-latency source per R4 counters). LDS 72KB -> 2 blocks/CU.
// ---------------------------------------------------------------------------
#define XS_STRIDE 264   // 240+24 pad bf16
#define O1_STRIDE 520   // 512+8 pad bf16

// LDS byte map (73728 total):
//   [0,33792)      Xs  [64][264] bf16
//   [33792,67584)  Hs  [64][264] bf16
//   [0,66560)      O1s [64][520] bf16   (overlays Xs+Hs after GEMM2-acc barrier)
//   [67584,71680)  Mbits[1024] u32      (u2 keep-mask, bit f = row*512+n)
//   [71680,73728)  InnoS [64][8] f32
__global__ __launch_bounds__(512, 2) void k_main(
    const float* __restrict__ x_in0, const float* __restrict__ u1,
    const float* __restrict__ u2,
    const __hip_bfloat16* __restrict__ Wihb, const float* __restrict__ ghb,
    const float* __restrict__ h_init,
    const __hip_bfloat16* __restrict__ Wo1b, const float* __restrict__ b_out1,
    const __hip_bfloat16* __restrict__ Wo2b, const float* __restrict__ b_out2,
    const float* __restrict__ x_pred, const float* __restrict__ inno,
    float* __restrict__ ens)
{
    __shared__ __align__(16) char smem[73728];
    __hip_bfloat16* Xs  = (__hip_bfloat16*)smem;            // [64][264]
    __hip_bfloat16* Hs  = (__hip_bfloat16*)(smem + 33792);  // [64][264]
    __hip_bfloat16* O1s = (__hip_bfloat16*)smem;            // [64][520], overlays Xs+Hs
    unsigned int* Mbits = (unsigned int*)(smem + 67584);    // [1024]
    float* InnoS = (float*)(smem + 71680);                  // [64][8]

    const int tid = threadIdx.x;
    const int j  = blockIdx.x >> 6;          // 64 blocks per j
    const int b0 = (blockIdx.x & 63) << 6;   // 64 b-rows per block

    // ---- phase 0a: u2 keep-mask -> Mbits (coalesced float4 over contiguous 128KB) ----
    {
        const float4* u2t = (const float4*)(u2 + ((size_t)(j*B_DIM + b0) << 9));
        const int sh = (tid & 7) * 4;
        #pragma unroll
        for (int it = 0; it < 16; ++it) {
            float4 q = u2t[tid + 512*it];
            unsigned int nib = (q.x > 0.65f ? 1u : 0u) | (q.y > 0.65f ? 2u : 0u)
                             | (q.z > 0.65f ? 4u : 0u) | (q.w > 0.65f ? 8u : 0u);
            unsigned int v = nib << sh;
            v |= __shfl_xor(v, 1);
            v |= __shfl_xor(v, 2);
            v |= __shfl_xor(v, 4);
            if ((tid & 7) == 0) Mbits[(tid >> 3) + 64*it] = v;
        }
    }

    // ---- phase 0b: stage masked bf16 X tile (float4, contiguous 60KB tiles) ----
    {
        const float4* xt = (const float4*)(x_in0 + b0*240);
        const float4* ut = (const float4*)(u1 + (size_t)(j*B_DIM + b0)*240);
        #pragma unroll
        for (int it = 0; it < 8; ++it) {
            int idx = tid + 512*it;
            if (idx < 3840) {
                float4 xv = xt[idx];
                float4 uv = ut[idx];
                int i = idx / 60;                 // 60 float4 per row (240 floats)
                int h = (idx - i*60) * 4;         // multiple of 4
                __align__(8) __hip_bfloat16 o[4];
                o[0] = __float2bfloat16(uv.x > 0.5f ? 2.0f*xv.x : 0.0f);
                o[1] = __float2bfloat16(uv.y > 0.5f ? 2.0f*xv.y : 0.0f);
                o[2] = __float2bfloat16(uv.z > 0.5f ? 2.0f*xv.z : 0.0f);
                o[3] = __float2bfloat16(uv.w > 0.5f ? 2.0f*xv.w : 0.0f);
                *(uint2*)&Xs[i*XS_STRIDE + h] = *(const uint2*)o;
            }
        }
    }
    // zero K-pad cols [240,256) for Xs and Hs (MFMA reads up to col 256)
    if (tid < 256) {
        int row = tid >> 2, c = 240 + ((tid & 3) << 2);
        uint2 z = {0u, 0u};
        *(uint2*)&Xs[row*XS_STRIDE + c] = z;
        *(uint2*)&Hs[row*XS_STRIDE + c] = z;
    }
    InnoS[tid & 511] = inno[b0*8 + (tid & 511)];   // 512 values
    __syncthreads();

    const int wave = tid >> 6;
    const int l15  = tid & 15;
    const int quad = (tid >> 4) & 3;
    const f32x4 zero4 = {0.f, 0.f, 0.f, 0.f};
    const int fragoff = quad*128 + l15*8;     // lane offset inside a fragment-major tile

    // ---- GEMM1: gx = X @ W_ih^T, 15 h-tiles over 8 waves (2 slots) ----
    #pragma unroll 1
    for (int sl = 0; sl < 2; ++sl) {
        const int t = wave + 8*sl;
        if (t < 15) {                        // wave 7 idle on sl=1 (wave-uniform)
            f32x4 aR[4], aZ[4], aN[4];
            #pragma unroll
            for (int m = 0; m < 4; ++m) { aR[m] = zero4; aZ[m] = zero4; aN[m] = zero4; }

            // fragment-major: tile t (r-gate), t+15 (z), t+30 (n); tile stride 4096
            const __hip_bfloat16* wr = Wihb + t*4096 + fragoff;
            #pragma unroll
            for (int ks = 0; ks < 8; ++ks) {
                const int ko = ks*32 + quad*8;
                bf16x8 a[4];
                #pragma unroll
                for (int m = 0; m < 4; ++m)
                    a[m] = *(const bf16x8*)&Xs[(m*16 + l15)*XS_STRIDE + ko];
                bf16x8 br = *(const bf16x8*)&wr[ks*512];
                bf16x8 bz = *(const bf16x8*)&wr[61440 + ks*512];    // +15 tiles
                bf16x8 bn = *(const bf16x8*)&wr[122880 + ks*512];   // +30 tiles
                #pragma unroll
                for (int m = 0; m < 4; ++m) {
                    aR[m] = MFMA16(a[m], br, aR[m]);
                    aZ[m] = MFMA16(a[m], bz, aZ[m]);
                    aN[m] = MFMA16(a[m], bn, aN[m]);
                }
            }
            // GRU nonlinearity -> Hs (bf16), native exp/rcp
            const int h = t*16 + l15;
            const float add_r = ghb[h],       add_z = ghb[240 + h];
            const float add_n = ghb[480 + h], mul_n = ghb[720 + h];
            const float hi = h_init[h];
            #pragma unroll
            for (int m = 0; m < 4; ++m)
                #pragma unroll
                for (int r = 0; r < 4; ++r) {
                    const int row = m*16 + quad*4 + r;
                    float rg = fast_sigmoid(aR[m][r] + add_r);
                    float zg = fast_sigmoid(aZ[m][r] + add_z);
                    float ng = fast_tanh(aN[m][r] + add_n + rg*mul_n);
                    Hs[row*XS_STRIDE + h] = __float2bfloat16(fmaf(zg, hi - ng, ng));
                }
        }
    }
    __syncthreads();

    // ---- GEMM2: o1 = relu(H @ W_out1^T + b)*mask2  (N=512, 4 tiles/wave) ----
    {
        f32x4 acc2[4][4];
        #pragma unroll
        for (int it = 0; it < 4; ++it)
            #pragma unroll
            for (int m = 0; m < 4; ++m) acc2[it][m] = zero4;

        const __hip_bfloat16* w2 = Wo1b + wave*16384 + fragoff;   // 4 tiles/wave
        #pragma unroll
        for (int ks = 0; ks < 8; ++ks) {
            bf16x8 a[4];
            const int ko = ks*32 + quad*8;
            #pragma unroll
            for (int m = 0; m < 4; ++m)
                a[m] = *(const bf16x8*)&Hs[(m*16 + l15)*XS_STRIDE + ko];
            #pragma unroll
            for (int it = 0; it < 4; ++it) {
                bf16x8 b = *(const bf16x8*)&w2[it*4096 + ks*512];
                #pragma unroll
                for (int m = 0; m < 4; ++m)
                    acc2[it][m] = MFMA16(a[m], b, acc2[it][m]);
            }
        }
        __syncthreads();   // Hs/Xs now dead; O1s may overlay them
        const float inv35 = 1.0f/0.35f;
        #pragma unroll
        for (int it = 0; it < 4; ++it) {
            const int n = (wave*4 + it)*16 + l15;
            const float bb = b_out1[n];
            const int wbase = (wave*4 + it) >> 1;      // n>>5
            const int bitpos = ((it & 1) << 4) | l15;  // n&31
            #pragma unroll
            for (int m = 0; m < 4; ++m)
                #pragma unroll
                for (int r = 0; r < 4; ++r) {
                    const int row = m*16 + quad*4 + r;
                    unsigned int mw = Mbits[row*16 + wbase];
                    float o = fmaxf(acc2[it][m][r] + bb, 0.0f);
                    o = ((mw >> bitpos) & 1u) ? o*inv35 : 0.0f;
                    O1s[row*O1_STRIDE + n] = __float2bfloat16(o);
                }
        }
    }
    __syncthreads();

    // ---- GEMM3: K = o1 @ W_out2^T + b; corr = K.inno; ensemble write ----
    {
        const int n = wave*16 + l15;          // 8 waves x 16 = N=128
        const float bo = b_out2[n];
        f32x4 acc3[4];
        #pragma unroll
        for (int m = 0; m < 4; ++m) { f32x4 v = {bo, bo, bo, bo}; acc3[m] = v; }

        const __hip_bfloat16* w3 = Wo2b + wave*8192 + fragoff;    // 1 tile/wave, 16 ks
        #pragma unroll
        for (int ks = 0; ks < 16; ++ks) {
            const int ko = ks*32 + quad*8;
            bf16x8 b = *(const bf16x8*)&w3[ks*512];
            #pragma unroll
            for (int m = 0; m < 4; ++m) {
                bf16x8 a = *(const bf16x8*)&O1s[(m*16 + l15)*O1_STRIDE + ko];
                acc3[m] = MFMA16(a, b, acc3[m]);
            }
        }
        const int s = n >> 3, o = n & 7;
        #pragma unroll
        for (int m = 0; m < 4; ++m)
            #pragma unroll
            for (int r = 0; r < 4; ++r) {
                const int row = m*16 + quad*4 + r;
                float v = acc3[m][r] * InnoS[row*8 + o];
                v += __shfl_xor(v, 1);
                v += __shfl_xor(v, 2);
                v += __shfl_xor(v, 4);
                if (o == 0)
                    ens[((b0 + row)*J_DIM + j)*16 + s] = x_pred[(b0 + row)*16 + s] + v;
            }
    }
}

// ---------------------------------------------------------------------------
// final: mean/var(ddof=1) over J per (b,s) + reg scalar
// ---------------------------------------------------------------------------
__global__ void k_final(const float* __restrict__ ens, float* __restrict__ out)
{
    int t = blockIdx.x * 256 + threadIdx.x;   // 65536 = B*S
    int b = t >> 4, s = t & 15;
    float v[32];
    #pragma unroll
    for (int jj = 0; jj < 32; jj++) v[jj] = ens[(b*32 + jj)*16 + s];
    float m = 0.f;
    #pragma unroll
    for (int jj = 0; jj < 32; jj++) m += v[jj];
    m *= (1.0f/32.0f);
    float var = 0.f;
    #pragma unroll
    for (int jj = 0; jj < 32; jj++) { float d = v[jj] - m; var = fmaf(d, d, var); }
    var *= (1.0f/31.0f);
    out[OUT_X + t] = m;
    out[OUT_P + t] = var;
    if (t == 0) out[OUT_REG] = 1.3405938195945778f;  // ln2 + H(0.65)
}

// ---------------------------------------------------------------------------
extern "C" void kernel_launch(void* const* d_in, const int* in_sizes, int n_in,
                              void* d_out, int out_size, void* d_ws, size_t ws_size,
                              hipStream_t stream)
{
    (void)in_sizes; (void)n_in; (void)out_size; (void)ws_size;
    const float* y_t    = (const float*)d_in[0];
    const float* xprev  = (const float*)d_in[1];
    const float* F      = (const float*)d_in[2];
    const float* Hm     = (const float*)d_in[3];
    const float* Wfc    = (const float*)d_in[4];
    const float* bfc    = (const float*)d_in[5];
    const float* W_ih   = (const float*)d_in[6];
    const float* W_hh   = (const float*)d_in[7];
    const float* b_ih   = (const float*)d_in[8];
    const float* b_hh   = (const float*)d_in[9];
    const float* W_o1   = (const float*)d_in[10];
    const float* b_o1   = (const float*)d_in[11];
    const float* W_o2   = (const float*)d_in[12];
    const float* b_o2   = (const float*)d_in[13];
    const float* h_init = (const float*)d_in[14];
    const float* u1     = (const float*)d_in[15];
    const float* u2     = (const float*)d_in[16];

    float* out = (float*)d_out;
    float* ws  = (float*)d_ws;
    float* x_pred = ws + WS_XPRED;
    float* inno   = ws + WS_INNO;
    float* feats  = ws + WS_FEATS;
    float* x_in0  = ws + WS_XIN0;
    float* ghb    = ws + WS_GH;
    __hip_bfloat16* Wihb = (__hip_bfloat16*)((char*)d_ws + WS_WB_OFF);
    __hip_bfloat16* Wo1b = Wihb + 768*256;
    __hip_bfloat16* Wo2b = Wo1b + 512*256;
    float* ens    = out + OUT_ENS;

    k_aux_pre<<<dim3(1552), dim3(256), 0, stream>>>(W_ih, W_hh, b_ih, b_hh, h_init,
                                                    W_o1, W_o2, Wihb, Wo1b, Wo2b, ghb,
                                                    y_t, xprev, F, Hm, x_pred, inno, feats);
    k_pre_b<<<dim3(3840), dim3(256), 0, stream>>>(feats, Wfc, bfc, x_in0);
    k_main<<<dim3(2048), dim3(512), 0, stream>>>(x_in0, u1, u2, Wihb, ghb, h_init,
                                                 Wo1b, b_o1, Wo2b, b_o2,
                                                 x_pred, inno, ens);
    k_final<<<dim3(256), dim3(256), 0, stream>>>(ens, out);
}

// Round 6
// 707.458 us; speedup vs baseline: 1.2294x; 1.0655x over previous
//
#include <hip/hip_runtime.h>
#include <hip/hip_bf16.h>
#include <math.h>

#define S_DIM 16
#define O_DIM 8
#define J_DIM 32
#define B_DIM 4096
#define HID 240
#define OHID 512

typedef __attribute__((ext_vector_type(8))) short bf16x8;
typedef __attribute__((ext_vector_type(4))) float f32x4;
#define MFMA16(a,b,c) __builtin_amdgcn_mfma_f32_16x16x32_bf16((a),(b),(c),0,0,0)

static __device__ __forceinline__ float fast_rcp(float x) { return __builtin_amdgcn_rcpf(x); }
static __device__ __forceinline__ float fast_sigmoid(float x) {
    return fast_rcp(1.0f + __expf(-x));
}
static __device__ __forceinline__ float fast_tanh(float x) {
    float t = __expf(2.0f * x);                   // inf-safe: rcp(inf)=0 -> 1; t=0 -> -1
    return 1.0f - 2.0f * fast_rcp(t + 1.0f);
}

// ---------------------------------------------------------------------------
// ws layout
// fp32 region (float offsets):
#define WS_XPRED   0                                  // [B,16]
#define WS_INNO    (WS_XPRED + B_DIM*S_DIM)           // [B,8]
#define WS_FEATS   (WS_INNO + B_DIM*O_DIM)            // [B,48]
#define WS_GH      (WS_FEATS + B_DIM*48)              // [960]
#define WS_BYTE    ((WS_GH + 960) * 4)                // byte offset of packed region
// byte region:
//   xb   : B*240 bf16 (= bf16(2*relu(fc_in)), j-independent)     1,966,080 B
//   Wihb : 196608 bf16 (fragment-major, 48 tiles)                  393,216 B
//   Wo1b : 131072 bf16 (fragment-major, 32 tiles)                  262,144 B
//   Wo2b :  65536 bf16 (fragment-major,  8 tiles)                  131,072 B
//   M1   : 131072 rows x 8 u32  (u1>0.5 bits, col c -> word c>>5)  4,194,304 B
//   M2   : 131072 rows x 16 u32 (u2>0.65 bits, n -> word n>>5)     8,388,608 B
// fragment-major weights: flat = (((tile*KS+ks)*4+q)*16+l)*8+e ;
//   row=tile*16+l, col=ks*32+q*8+e -> wave fragment load = 1KB contiguous.

// out layout (float offsets)
#define OUT_X      0
#define OUT_P      (B_DIM*S_DIM)                      // 65536
#define OUT_REG    (2*B_DIM*S_DIM)                    // 131072
#define OUT_ENS    (2*B_DIM*S_DIM + 1)                // 131073

// ---------------------------------------------------------------------------
// aux+pre_a: blocks [0,1536) build fragment-major bf16 weights + GRU gh
// precompute; blocks [1536,1552) do the Kalman prefix per b.
// ---------------------------------------------------------------------------
__global__ void k_aux_pre(const float* __restrict__ W_ih, const float* __restrict__ W_hh,
                          const float* __restrict__ b_ih, const float* __restrict__ b_hh,
                          const float* __restrict__ h_init,
                          const float* __restrict__ W_o1, const float* __restrict__ W_o2,
                          __hip_bfloat16* __restrict__ Wihb, __hip_bfloat16* __restrict__ Wo1b,
                          __hip_bfloat16* __restrict__ Wo2b, float* __restrict__ ghb,
                          const float* __restrict__ y, const float* __restrict__ xprev,
                          const float* __restrict__ F, const float* __restrict__ Hm,
                          float* __restrict__ x_pred, float* __restrict__ inno,
                          float* __restrict__ feats)
{
    __shared__ float sF[256], sH[128];
    const int tid = threadIdx.x;
    if (blockIdx.x < 1536) {
        int t = blockIdx.x * 256 + tid;
        if (t < 196608) {                               // Wihb (768x256)
            int e = t & 7, l = (t >> 3) & 15, q = (t >> 7) & 3;
            int ks = (t >> 9) & 7, tile = t >> 12;
            int row = tile*16 + l, col = ks*32 + q*8 + e;
            float v = (row < 720 && col < 240) ? W_ih[row*240 + col] : 0.0f;
            Wihb[t] = __float2bfloat16(v);
        } else if (t < 196608 + 131072) {               // Wo1b (512x256)
            int u = t - 196608;
            int e = u & 7, l = (u >> 3) & 15, q = (u >> 7) & 3;
            int ks = (u >> 9) & 7, tile = u >> 12;
            int row = tile*16 + l, col = ks*32 + q*8 + e;
            float v = (col < 240) ? W_o1[row*240 + col] : 0.0f;
            Wo1b[u] = __float2bfloat16(v);
        } else if (t < 393216) {                        // Wo2b (128x512)
            int u = t - 327680;
            int e = u & 7, l = (u >> 3) & 15, q = (u >> 7) & 3;
            int ks = (u >> 9) & 15, tile = u >> 13;
            int row = tile*16 + l, col = ks*32 + q*8 + e;
            Wo2b[u] = __float2bfloat16(W_o2[row*512 + col]);
        }
        if (t < 720) {
            float a = b_hh[t];
            const float* wr = W_hh + t*240;
            for (int k = 0; k < 240; k++) a = fmaf(h_init[k], wr[k], a);
            if (t < 480) {
                ghb[t] = b_ih[t] + a;            // r/z gates: bias fully folded
            } else {
                ghb[t] = b_ih[t];                // n gate: additive part
                ghb[t + 240] = a;                // n gate: part multiplied by r
            }
        }
        return;
    }
    // ---- pre_a part ----
    sF[tid] = F[tid];
    if (tid < 128) sH[tid] = Hm[tid];
    __syncthreads();
    int b = (blockIdx.x - 1536) * 256 + tid;
    float xf[16], xp[16], inn[8];
    #pragma unroll
    for (int s = 0; s < 16; s++) xf[s] = xprev[b*16 + s];
    #pragma unroll
    for (int s = 0; s < 16; s++) {
        float a = 0.f;
        #pragma unroll
        for (int k = 0; k < 16; k++) a = fmaf(xf[k], sF[s*16 + k], a);
        xp[s] = a;
    }
    #pragma unroll
    for (int o = 0; o < 8; o++) {
        float a = 0.f;
        #pragma unroll
        for (int k = 0; k < 16; k++) a = fmaf(xp[k], sH[o*16 + k], a);
        inn[o] = y[b*8 + o] - a;
    }
    #pragma unroll
    for (int s = 0; s < 16; s++) x_pred[b*16 + s] = xp[s];
    #pragma unroll
    for (int o = 0; o < 8; o++) inno[b*8 + o] = inn[o];
    float* fb = feats + b*48;
    #pragma unroll
    for (int s = 0; s < 16; s++) fb[s] = xf[s] - xp[s];
    #pragma unroll
    for (int o = 0; o < 8; o++) fb[16 + o] = inn[o];
    #pragma unroll
    for (int s = 0; s < 16; s++) fb[24 + s] = 0.f;
    #pragma unroll
    for (int o = 0; o < 8; o++) fb[40 + o] = inn[o];
}

// ---------------------------------------------------------------------------
// pre_b: xb = bf16(2 * relu(feats @ W_fc^T + b_fc))   (pre-scaled for dropout)
// ---------------------------------------------------------------------------
__global__ void k_pre_b(const float* __restrict__ feats, const float* __restrict__ Wfc,
                        const float* __restrict__ bfc, __hip_bfloat16* __restrict__ xb)
{
    int t = blockIdx.x * 256 + threadIdx.x;
    int b = t / 240, h = t - b*240;
    const float* fb = feats + b*48;
    const float* wr = Wfc + h*48;
    float a = bfc[h];
    #pragma unroll
    for (int k = 0; k < 48; k += 4) {
        const float4 f4 = *(const float4*)&fb[k];
        const float4 w4 = *(const float4*)&wr[k];
        a = fmaf(f4.x, w4.x, fmaf(f4.y, w4.y, fmaf(f4.z, w4.z, fmaf(f4.w, w4.w, a))));
    }
    xb[t] = __float2bfloat16(2.0f * fmaxf(a, 0.f));
}

// ---------------------------------------------------------------------------
// pack: stream u1,u2 ONCE at full HBM BW -> 1-bit masks. BW-bound by design:
// tiny LDS-free blocks, full occupancy, coalesced float4. Removes the 394MB
// cold stream from k_main's barrier-phased (latency-bound) phase 0.
//   M1[row][8 u32]:  bit (c&31) of word c>>5  = u1[row][c] > 0.5
//   M2[row][16 u32]: bit (n&31) of word n>>5  = u2[row][n] > 0.65
// ---------------------------------------------------------------------------
__global__ __launch_bounds__(256) void k_pack(
    const float* __restrict__ u1, const float* __restrict__ u2,
    unsigned int* __restrict__ M1, unsigned int* __restrict__ M2)
{
    const int tid = threadIdx.x;
    const size_t f0 = (size_t)blockIdx.x * 64;     // 64 flat (j,b) rows per block
    // ---- u1 -> M1: 1024 tasks (64 rows x 16), task t covers cols [16t,16t+16) ----
    {
        const float4* u1t = (const float4*)(u1 + f0 * 240);
        #pragma unroll
        for (int it = 0; it < 4; ++it) {
            int task = tid + 256*it;
            int row = task >> 4, t = task & 15;
            unsigned int bits = 0;
            if (t < 15) {                          // t=15: virtual cols 240-255 -> 0
                const float4* p = u1t + row*60 + t*4;
                #pragma unroll
                for (int q = 0; q < 4; ++q) {
                    float4 v = p[q];
                    bits |= (v.x > 0.5f ? 1u : 0u) << (q*4);
                    bits |= (v.y > 0.5f ? 2u : 0u) << (q*4);
                    bits |= (v.z > 0.5f ? 4u : 0u) << (q*4);
                    bits |= (v.w > 0.5f ? 8u : 0u) << (q*4);
                }
            }
            unsigned int other = __shfl_xor(bits, 1);   // partner task^1 == lane^1
            if ((t & 1) == 0)
                M1[(f0 + row)*8 + (t >> 1)] = bits | (other << 16);
        }
    }
    // ---- u2 -> M2: 8192 float4, word = idx>>3 (8 lanes combine) ----
    {
        const float4* u2t = (const float4*)(u2 + f0 * 512);
        const int sh = (tid & 7) * 4;
        #pragma unroll 8
        for (int it = 0; it < 32; ++it) {
            int idx = tid + 256*it;
            float4 q = u2t[idx];
            unsigned int nib = (q.x > 0.65f ? 1u : 0u) | (q.y > 0.65f ? 2u : 0u)
                             | (q.z > 0.65f ? 4u : 0u) | (q.w > 0.65f ? 8u : 0u);
            unsigned int v = nib << sh;
            v |= __shfl_xor(v, 1);
            v |= __shfl_xor(v, 2);
            v |= __shfl_xor(v, 4);
            if ((tid & 7) == 0) M2[f0*16 + (idx >> 3)] = v;
        }
    }
}

// ---------------------------------------------------------------------------
// main: bf16 MFMA fused chain. M=64 rows/block, 512 thr (8 waves), grid 2048.
// Phase 0 now reads ~38KB of warm packed data (xb reused by all 32 j's,
// masks 1 bit/element) instead of 256KB cold fp32 stream.
// ---------------------------------------------------------------------------
#define XS_STRIDE 264   // 240+24 pad bf16
#define O1_STRIDE 520   // 512+8 pad bf16

// LDS byte map (73728 total):
//   [0,33792)      Xs  [64][264] bf16
//   [33792,67584)  Hs  [64][264] bf16
//   [0,66560)      O1s [64][520] bf16   (overlays Xs+Hs after GEMM2-acc barrier)
//   [67584,71680)  Mbits[1024] u32      (u2 keep-mask)
//   [71680,73728)  InnoS [64][8] f32
__global__ __launch_bounds__(512, 2) void k_main(
    const __hip_bfloat16* __restrict__ xb,
    const unsigned int* __restrict__ M1, const unsigned int* __restrict__ M2,
    const __hip_bfloat16* __restrict__ Wihb, const float* __restrict__ ghb,
    const float* __restrict__ h_init,
    const __hip_bfloat16* __restrict__ Wo1b, const float* __restrict__ b_out1,
    const __hip_bfloat16* __restrict__ Wo2b, const float* __restrict__ b_out2,
    const float* __restrict__ x_pred, const float* __restrict__ inno,
    float* __restrict__ ens)
{
    __shared__ __align__(16) char smem[73728];
    __hip_bfloat16* Xs  = (__hip_bfloat16*)smem;            // [64][264]
    __hip_bfloat16* Hs  = (__hip_bfloat16*)(smem + 33792);  // [64][264]
    __hip_bfloat16* O1s = (__hip_bfloat16*)smem;            // [64][520], overlays Xs+Hs
    unsigned int* Mbits = (unsigned int*)(smem + 67584);    // [1024]
    float* InnoS = (float*)(smem + 71680);                  // [64][8]

    const int tid = threadIdx.x;
    const int j  = blockIdx.x >> 6;          // 64 blocks per j
    const int b0 = (blockIdx.x & 63) << 6;   // 64 b-rows per block
    const size_t f0 = (size_t)j * B_DIM + b0;   // flat (j,b) row base

    // ---- phase 0a: M2 -> Mbits (coalesced dwords) ----
    Mbits[tid]       = M2[f0*16 + tid];
    Mbits[tid + 512] = M2[f0*16 + tid + 512];

    // ---- phase 0b: stage masked X tile: xb (pre-scaled bf16) AND'ed by M1 bits ----
    {
        #pragma unroll
        for (int it = 0; it < 4; ++it) {
            int idx = tid + 512*it;               // 1920 chunks: row = idx/30, 8 cols
            if (idx < 1920) {
                int row = idx / 30;
                int c8  = idx - row*30;
                uint4 xv = *(const uint4*)(xb + ((size_t)(b0 + row)*240 + c8*8));
                unsigned int m1w = M1[(f0 + row)*8 + (c8 >> 2)];
                unsigned int bits = (m1w >> ((c8 & 3) * 8)) & 0xffu;
                unsigned int w0 = xv.x, w1 = xv.y, w2 = xv.z, w3 = xv.w;
                w0 &= ((bits & 1u) ? 0x0000ffffu : 0u) | ((bits & 2u)   ? 0xffff0000u : 0u);
                w1 &= ((bits & 4u) ? 0x0000ffffu : 0u) | ((bits & 8u)   ? 0xffff0000u : 0u);
                w2 &= ((bits & 16u)? 0x0000ffffu : 0u) | ((bits & 32u)  ? 0xffff0000u : 0u);
                w3 &= ((bits & 64u)? 0x0000ffffu : 0u) | ((bits & 128u) ? 0xffff0000u : 0u);
                uint4 o = {w0, w1, w2, w3};
                *(uint4*)&Xs[row*XS_STRIDE + c8*8] = o;
            }
        }
    }
    // zero K-pad cols [240,256) for Xs and Hs (MFMA reads up to col 256)
    if (tid < 256) {
        int row = tid >> 2, c = 240 + ((tid & 3) << 2);
        uint2 z = {0u, 0u};
        *(uint2*)&Xs[row*XS_STRIDE + c] = z;
        *(uint2*)&Hs[row*XS_STRIDE + c] = z;
    }
    InnoS[tid & 511] = inno[b0*8 + (tid & 511)];   // 512 values
    __syncthreads();

    const int wave = tid >> 6;
    const int l15  = tid & 15;
    const int quad = (tid >> 4) & 3;
    const f32x4 zero4 = {0.f, 0.f, 0.f, 0.f};
    const int fragoff = quad*128 + l15*8;     // lane offset inside a fragment-major tile

    // ---- GEMM1: gx = X @ W_ih^T, 15 h-tiles over 8 waves (2 slots) ----
    #pragma unroll 1
    for (int sl = 0; sl < 2; ++sl) {
        const int t = wave + 8*sl;
        if (t < 15) {                        // wave 7 idle on sl=1 (wave-uniform)
            f32x4 aR[4], aZ[4], aN[4];
            #pragma unroll
            for (int m = 0; m < 4; ++m) { aR[m] = zero4; aZ[m] = zero4; aN[m] = zero4; }

            const __hip_bfloat16* wr = Wihb + t*4096 + fragoff;
            #pragma unroll
            for (int ks = 0; ks < 8; ++ks) {
                const int ko = ks*32 + quad*8;
                bf16x8 a[4];
                #pragma unroll
                for (int m = 0; m < 4; ++m)
                    a[m] = *(const bf16x8*)&Xs[(m*16 + l15)*XS_STRIDE + ko];
                bf16x8 br = *(const bf16x8*)&wr[ks*512];
                bf16x8 bz = *(const bf16x8*)&wr[61440 + ks*512];    // +15 tiles
                bf16x8 bn = *(const bf16x8*)&wr[122880 + ks*512];   // +30 tiles
                #pragma unroll
                for (int m = 0; m < 4; ++m) {
                    aR[m] = MFMA16(a[m], br, aR[m]);
                    aZ[m] = MFMA16(a[m], bz, aZ[m]);
                    aN[m] = MFMA16(a[m], bn, aN[m]);
                }
            }
            // GRU nonlinearity -> Hs (bf16), native exp/rcp
            const int h = t*16 + l15;
            const float add_r = ghb[h],       add_z = ghb[240 + h];
            const float add_n = ghb[480 + h], mul_n = ghb[720 + h];
            const float hi = h_init[h];
            #pragma unroll
            for (int m = 0; m < 4; ++m)
                #pragma unroll
                for (int r = 0; r < 4; ++r) {
                    const int row = m*16 + quad*4 + r;
                    float rg = fast_sigmoid(aR[m][r] + add_r);
                    float zg = fast_sigmoid(aZ[m][r] + add_z);
                    float ng = fast_tanh(aN[m][r] + add_n + rg*mul_n);
                    Hs[row*XS_STRIDE + h] = __float2bfloat16(fmaf(zg, hi - ng, ng));
                }
        }
    }
    __syncthreads();

    // ---- GEMM2: o1 = relu(H @ W_out1^T + b)*mask2  (N=512, 4 tiles/wave) ----
    {
        f32x4 acc2[4][4];
        #pragma unroll
        for (int it = 0; it < 4; ++it)
            #pragma unroll
            for (int m = 0; m < 4; ++m) acc2[it][m] = zero4;

        const __hip_bfloat16* w2 = Wo1b + wave*16384 + fragoff;   // 4 tiles/wave
        #pragma unroll
        for (int ks = 0; ks < 8; ++ks) {
            bf16x8 a[4];
            const int ko = ks*32 + quad*8;
            #pragma unroll
            for (int m = 0; m < 4; ++m)
                a[m] = *(const bf16x8*)&Hs[(m*16 + l15)*XS_STRIDE + ko];
            #pragma unroll
            for (int it = 0; it < 4; ++it) {
                bf16x8 b = *(const bf16x8*)&w2[it*4096 + ks*512];
                #pragma unroll
                for (int m = 0; m < 4; ++m)
                    acc2[it][m] = MFMA16(a[m], b, acc2[it][m]);
            }
        }
        __syncthreads();   // Hs/Xs now dead; O1s may overlay them
        const float inv35 = 1.0f/0.35f;
        #pragma unroll
        for (int it = 0; it < 4; ++it) {
            const int n = (wave*4 + it)*16 + l15;
            const float bb = b_out1[n];
            const int wbase = (wave*4 + it) >> 1;      // n>>5
            const int bitpos = ((it & 1) << 4) | l15;  // n&31
            #pragma unroll
            for (int m = 0; m < 4; ++m)
                #pragma unroll
                for (int r = 0; r < 4; ++r) {
                    const int row = m*16 + quad*4 + r;
                    unsigned int mw = Mbits[row*16 + wbase];
                    float o = fmaxf(acc2[it][m][r] + bb, 0.0f);
                    o = ((mw >> bitpos) & 1u) ? o*inv35 : 0.0f;
                    O1s[row*O1_STRIDE + n] = __float2bfloat16(o);
                }
        }
    }
    __syncthreads();

    // ---- GEMM3: K = o1 @ W_out2^T + b; corr = K.inno; ensemble write ----
    {
        const int n = wave*16 + l15;          // 8 waves x 16 = N=128
        const float bo = b_out2[n];
        f32x4 acc3[4];
        #pragma unroll
        for (int m = 0; m < 4; ++m) { f32x4 v = {bo, bo, bo, bo}; acc3[m] = v; }

        const __hip_bfloat16* w3 = Wo2b + wave*8192 + fragoff;    // 1 tile/wave, 16 ks
        #pragma unroll
        for (int ks = 0; ks < 16; ++ks) {
            const int ko = ks*32 + quad*8;
            bf16x8 b = *(const bf16x8*)&w3[ks*512];
            #pragma unroll
            for (int m = 0; m < 4; ++m) {
                bf16x8 a = *(const bf16x8*)&O1s[(m*16 + l15)*O1_STRIDE + ko];
                acc3[m] = MFMA16(a, b, acc3[m]);
            }
        }
        const int s = n >> 3, o = n & 7;
        #pragma unroll
        for (int m = 0; m < 4; ++m)
            #pragma unroll
            for (int r = 0; r < 4; ++r) {
                const int row = m*16 + quad*4 + r;
                float v = acc3[m][r] * InnoS[row*8 + o];
                v += __shfl_xor(v, 1);
                v += __shfl_xor(v, 2);
                v += __shfl_xor(v, 4);
                if (o == 0)
                    ens[((b0 + row)*J_DIM + j)*16 + s] = x_pred[(b0 + row)*16 + s] + v;
            }
    }
}

// ---------------------------------------------------------------------------
// final: mean/var(ddof=1) over J per (b,s) + reg scalar
// ---------------------------------------------------------------------------
__global__ void k_final(const float* __restrict__ ens, float* __restrict__ out)
{
    int t = blockIdx.x * 256 + threadIdx.x;   // 65536 = B*S
    int b = t >> 4, s = t & 15;
    float v[32];
    #pragma unroll
    for (int jj = 0; jj < 32; jj++) v[jj] = ens[(b*32 + jj)*16 + s];
    float m = 0.f;
    #pragma unroll
    for (int jj = 0; jj < 32; jj++) m += v[jj];
    m *= (1.0f/32.0f);
    float var = 0.f;
    #pragma unroll
    for (int jj = 0; jj < 32; jj++) { float d = v[jj] - m; var = fmaf(d, d, var); }
    var *= (1.0f/31.0f);
    out[OUT_X + t] = m;
    out[OUT_P + t] = var;
    if (t == 0) out[OUT_REG] = 1.3405938195945778f;  // ln2 + H(0.65)
}

// ---------------------------------------------------------------------------
extern "C" void kernel_launch(void* const* d_in, const int* in_sizes, int n_in,
                              void* d_out, int out_size, void* d_ws, size_t ws_size,
                              hipStream_t stream)
{
    (void)in_sizes; (void)n_in; (void)out_size; (void)ws_size;
    const float* y_t    = (const float*)d_in[0];
    const float* xprev  = (const float*)d_in[1];
    const float* F      = (const float*)d_in[2];
    const float* Hm     = (const float*)d_in[3];
    const float* Wfc    = (const float*)d_in[4];
    const float* bfc    = (const float*)d_in[5];
    const float* W_ih   = (const float*)d_in[6];
    const float* W_hh   = (const float*)d_in[7];
    const float* b_ih   = (const float*)d_in[8];
    const float* b_hh   = (const float*)d_in[9];
    const float* W_o1   = (const float*)d_in[10];
    const float* b_o1   = (const float*)d_in[11];
    const float* W_o2   = (const float*)d_in[12];
    const float* b_o2   = (const float*)d_in[13];
    const float* h_init = (const float*)d_in[14];
    const float* u1     = (const float*)d_in[15];
    const float* u2     = (const float*)d_in[16];

    float* out = (float*)d_out;
    float* ws  = (float*)d_ws;
    float* x_pred = ws + WS_XPRED;
    float* inno   = ws + WS_INNO;
    float* feats  = ws + WS_FEATS;
    float* ghb    = ws + WS_GH;
    char* pb = (char*)d_ws + WS_BYTE;
    __hip_bfloat16* xb   = (__hip_bfloat16*)pb;                    // B*240
    __hip_bfloat16* Wihb = (__hip_bfloat16*)(pb + 1966080);
    __hip_bfloat16* Wo1b = Wihb + 196608;
    __hip_bfloat16* Wo2b = Wo1b + 131072;
    unsigned int*   M1   = (unsigned int*)(pb + 1966080 + 786432);
    unsigned int*   M2   = M1 + 131072*8;
    float* ens    = out + OUT_ENS;

    k_aux_pre<<<dim3(1552), dim3(256), 0, stream>>>(W_ih, W_hh, b_ih, b_hh, h_init,
                                                    W_o1, W_o2, Wihb, Wo1b, Wo2b, ghb,
                                                    y_t, xprev, F, Hm, x_pred, inno, feats);
    k_pre_b<<<dim3(3840), dim3(256), 0, stream>>>(feats, Wfc, bfc, xb);
    k_pack<<<dim3(2048), dim3(256), 0, stream>>>(u1, u2, M1, M2);
    k_main<<<dim3(2048), dim3(512), 0, stream>>>(xb, M1, M2, Wihb, ghb, h_init,
                                                 Wo1b, b_o1, Wo2b, b_o2,
                                                 x_pred, inno, ens);
    k_final<<<dim3(256), dim3(256), 0, stream>>>(ens, out);
}